// Round 4
// baseline (2419.657 us; speedup 1.0000x reference)
//
#include <hip/hip_runtime.h>

typedef __bf16 bf16_t;
typedef __bf16 bf16x8 __attribute__((ext_vector_type(8)));
typedef float f32x4 __attribute__((ext_vector_type(4)));

// Problem constants
constexpr int Tn = 4 * 2048;   // tokens = B*S
constexpr int Dd = 1024;
constexpr int Ff = 4096;
constexpr int Oo = 1024;
constexpr int NEXP = 6;        // 2 shared + 4 routed

// flag-conditional scalar input load (inputs may be f32 or bf16; detected at runtime)
__device__ __forceinline__ float ldin(const void* p, size_t i, int isf32) {
    return isf32 ? ((const float*)p)[i] : (float)((const bf16_t*)p)[i];
}

// ---------------- dtype detector ----------------
// f32 N(0,1) data: low 16 bits of each word are ~uniform mantissa bits -> the bf16-NaN
// pattern (exponent all-ones) appears with P~2^-8. Genuine bf16 data: never.
__global__ void detect_kernel(const unsigned int* __restrict__ xw, int* __restrict__ flag) {
    __shared__ int cnt;
    if (threadIdx.x == 0) cnt = 0;
    __syncthreads();
    int c = 0;
    for (int i = threadIdx.x; i < 16384; i += 256) {
        unsigned w = xw[i];
        if (((w >> 7) & 0xFFu) == 0xFFu) ++c;
    }
    atomicAdd(&cnt, c);
    __syncthreads();
    if (threadIdx.x == 0) flag[0] = (cnt >= 4) ? 1 : 0;
}

// ---------------- x -> bf16 ----------------
__global__ void cvt_x_kernel(const void* __restrict__ x, const int* __restrict__ flag,
                             bf16_t* __restrict__ xb) {
    int f = flag[0];
    size_t i = (size_t)blockIdx.x * 256 + threadIdx.x;
    xb[i] = (bf16_t)ldin(x, i, f);
}

// ---------------- convert+transpose: src(+eofs) [R][C] -> bf16 dst [C][R] ----------------
__global__ void cvt_transpose_kernel(const void* __restrict__ src, size_t eofs,
                                     const int* __restrict__ flag,
                                     bf16_t* __restrict__ dst, int R, int C) {
    __shared__ bf16_t tile[32][33];
    int f = flag[0];
    int c0 = blockIdx.x * 32, r0 = blockIdx.y * 32;
    int tx = threadIdx.x, ty = threadIdx.y;
    #pragma unroll
    for (int i = 0; i < 32; i += 8)
        tile[ty + i][tx] = (bf16_t)ldin(src, eofs + (size_t)(r0 + ty + i) * C + c0 + tx, f);
    __syncthreads();
    #pragma unroll
    for (int i = 0; i < 32; i += 8)
        dst[(size_t)(c0 + ty + i) * R + r0 + tx] = tile[tx][ty + i];
}

// ---------------- gating ----------------
__global__ void gate_kernel(const void* __restrict__ x, const void* __restrict__ gw,
                            const void* __restrict__ gb, const int* __restrict__ flag,
                            float* __restrict__ coef) {
    int f = flag[0];
    int t = blockIdx.x;
    int lane = threadIdx.x;  // 64 threads
    float a0 = 0.f, a1 = 0.f, a2 = 0.f, a3 = 0.f;
    for (int d = lane; d < Dd; d += 64) {
        float xv = ldin(x, (size_t)t * Dd + d, f);
        a0 += xv * ldin(gw, (size_t)d * 4 + 0, f);
        a1 += xv * ldin(gw, (size_t)d * 4 + 1, f);
        a2 += xv * ldin(gw, (size_t)d * 4 + 2, f);
        a3 += xv * ldin(gw, (size_t)d * 4 + 3, f);
    }
    #pragma unroll
    for (int off = 32; off; off >>= 1) {
        a0 += __shfl_xor(a0, off);
        a1 += __shfl_xor(a1, off);
        a2 += __shfl_xor(a2, off);
        a3 += __shfl_xor(a3, off);
    }
    if (lane == 0) {
        float l[4] = {a0 + ldin(gb, 0, f), a1 + ldin(gb, 1, f),
                      a2 + ldin(gb, 2, f), a3 + ldin(gb, 3, f)};
        float mx = fmaxf(fmaxf(l[0], l[1]), fmaxf(l[2], l[3]));
        float e[4], s = 0.f;
        #pragma unroll
        for (int i = 0; i < 4; ++i) { e[i] = expf(l[i] - mx); s += e[i]; }
        float w[4];
        #pragma unroll
        for (int i = 0; i < 4; ++i) w[i] = e[i] / s;
        int i0 = 0;
        for (int i = 1; i < 4; ++i) if (w[i] > w[i0]) i0 = i;   // ties -> lowest idx
        int i1 = -1;
        for (int i = 0; i < 4; ++i) { if (i == i0) continue; if (i1 < 0 || w[i] > w[i1]) i1 = i; }
        float c[8] = {0.5f, 0.5f, 0.f, 0.f, 0.f, 0.f, 0.f, 0.f};
        c[2 + i0] = w[i0];
        c[2 + i1] = w[i1];
        float* dst = coef + (size_t)t * 8;
        #pragma unroll
        for (int k = 0; k < 8; ++k) dst[k] = c[k];
    }
}

// ---------------- acc init: acc[t][o] = sum_j coef[t][j]*b2[j][o] ----------------
__global__ void init_acc_kernel(const float* __restrict__ coef, const void* __restrict__ sb2,
                                const void* __restrict__ rb2, const int* __restrict__ flag,
                                float* __restrict__ acc) {
    int f = flag[0];
    size_t idx = (size_t)blockIdx.x * 256 + threadIdx.x;
    int t = (int)(idx >> 10);          // O = 1024
    int o = (int)(idx & 1023);
    const float* c = coef + (size_t)t * 8;
    float v = c[0] * ldin(sb2, o, f) + c[1] * ldin(sb2, Oo + o, f)
            + c[2] * ldin(rb2, o, f) + c[3] * ldin(rb2, Oo + o, f)
            + c[4] * ldin(rb2, 2 * Oo + o, f) + c[5] * ldin(rb2, 3 * Oo + o, f);
    acc[idx] = v;
}

// ---------------- final convert ----------------
__global__ void convert_kernel(const float* __restrict__ acc, const int* __restrict__ flag,
                               void* __restrict__ out) {
    int f = flag[0];
    size_t idx = (size_t)blockIdx.x * 256 + threadIdx.x;
    float v = acc[idx];
    if (v != v) v = 333.0f;   // NaN sentinel for diagnosis
    if (f) ((float*)out)[idx] = v;
    else   ((bf16_t*)out)[idx] = (bf16_t)v;
}

// ---------------- GEMM core: C = A[M,K] * Bt[N,K]^T, 128x128 tile, BK=64 ----------------
// MODE 1: obf = bf16( relu(acc + bias[b1_e+n]) * coef[m*8] );  MODE 2: oacc += acc
template <int MODE>
__launch_bounds__(256, 2)
__global__ void gemm_kernel(const bf16_t* __restrict__ A, const bf16_t* __restrict__ Bt,
                            int M, int N, int K,
                            const void* __restrict__ bias, size_t b1_e,
                            const int* __restrict__ flag,
                            const float* __restrict__ coef,
                            bf16_t* __restrict__ obf, float* __restrict__ oacc) {
    constexpr int BM = 128, BN = 128, BK = 64;
    __shared__ __align__(16) bf16_t Al[BM * BK];  // [m][k], k contiguous
    __shared__ __align__(16) bf16_t Bl[BN * BK];  // [n][k], k contiguous

    const int tid = threadIdx.x;
    const int lane = tid & 63;
    const int wave = tid >> 6;
    const int wm = wave & 1, wn = wave >> 1;   // 2x2 wave grid, each wave 64x64
    const int bm = blockIdx.x * BM;
    const int bn = blockIdx.y * BN;
    const int l15 = lane & 15;
    const int l4 = lane >> 4;

    f32x4 acc[4][4] = {};

    for (int k0 = 0; k0 < K; k0 += BK) {
        #pragma unroll
        for (int it = 0; it < 4; ++it) {
            int q = it * 256 + tid;
            int row = q >> 3, c8 = q & 7;
            *(bf16x8*)&Al[q * 8] = *(const bf16x8*)(A + (size_t)(bm + row) * K + k0 + c8 * 8);
        }
        #pragma unroll
        for (int it = 0; it < 4; ++it) {
            int q = it * 256 + tid;
            int row = q >> 3, c8 = q & 7;
            *(bf16x8*)&Bl[q * 8] = *(const bf16x8*)(Bt + (size_t)(bn + row) * K + k0 + c8 * 8);
        }
        __syncthreads();
        #pragma unroll
        for (int kk = 0; kk < BK; kk += 32) {
            bf16x8 af[4], bfv[4];
            #pragma unroll
            for (int i = 0; i < 4; ++i)
                af[i] = *(const bf16x8*)&Al[(wm * 64 + i * 16 + l15) * BK + kk + l4 * 8];
            #pragma unroll
            for (int j = 0; j < 4; ++j)
                bfv[j] = *(const bf16x8*)&Bl[(wn * 64 + j * 16 + l15) * BK + kk + l4 * 8];
            #pragma unroll
            for (int i = 0; i < 4; ++i)
                #pragma unroll
                for (int j = 0; j < 4; ++j)
                    acc[i][j] = __builtin_amdgcn_mfma_f32_16x16x32_bf16(af[i], bfv[j], acc[i][j], 0, 0, 0);
        }
        __syncthreads();
    }

    if (MODE == 1) {
        int isf32 = flag[0];
        float bz[4];
        #pragma unroll
        for (int j = 0; j < 4; ++j)
            bz[j] = ldin(bias, b1_e + (size_t)(bn + wn * 64 + j * 16 + l15), isf32);
        #pragma unroll
        for (int i = 0; i < 4; ++i) {
            #pragma unroll
            for (int r = 0; r < 4; ++r) {
                int m = bm + wm * 64 + i * 16 + l4 * 4 + r;
                float cf = coef[(size_t)m * 8];
                #pragma unroll
                for (int j = 0; j < 4; ++j) {
                    float v = acc[i][j][r] + bz[j];
                    v = fmaxf(v, 0.f) * cf;
                    obf[(size_t)m * N + bn + wn * 64 + j * 16 + l15] = (bf16_t)v;
                }
            }
        }
    } else {
        #pragma unroll
        for (int i = 0; i < 4; ++i) {
            #pragma unroll
            for (int r = 0; r < 4; ++r) {
                int m = bm + wm * 64 + i * 16 + l4 * 4 + r;
                float* orow = oacc + (size_t)m * N + bn + wn * 64 + l15;
                #pragma unroll
                for (int j = 0; j < 4; ++j)
                    orow[j * 16] += acc[i][j][r];
            }
        }
    }
}

// ---------------- launcher ----------------
extern "C" void kernel_launch(void* const* d_in, const int* in_sizes, int n_in,
                              void* d_out, int out_size, void* d_ws, size_t ws_size,
                              hipStream_t stream) {
    const void* x      = d_in[0];
    const void* gate_w = d_in[1];
    const void* gate_b = d_in[2];
    const void* sw1    = d_in[3];
    const void* sb1    = d_in[4];
    const void* sw2    = d_in[5];
    const void* sb2    = d_in[6];
    const void* rw1    = d_in[7];
    const void* rb1    = d_in[8];
    const void* rw2    = d_in[9];
    const void* rb2    = d_in[10];

    char* ws = (char*)d_ws;
    int* flag = (int*)ws;
    size_t off = 256;
    bf16_t* W1T = (bf16_t*)(ws + off); off += (size_t)Ff * Dd * sizeof(bf16_t);  // 8 MB
    bf16_t* W2T = (bf16_t*)(ws + off); off += (size_t)Oo * Ff * sizeof(bf16_t);  // 8 MB
    bf16_t* xb  = (bf16_t*)(ws + off); off += (size_t)Tn * Dd * sizeof(bf16_t);  // 16 MB
    float* coef = (float*)(ws + off);  off += (size_t)Tn * 8 * sizeof(float);    // 256 KB
    float* accb = (float*)(ws + off);  off += (size_t)Tn * Oo * sizeof(float);   // 32 MB
    bf16_t* Hs  = (bf16_t*)(ws + off);
    size_t rem = (ws_size > off) ? (ws_size - off) : 0;
    long tcap = (long)(rem / ((size_t)Ff * sizeof(bf16_t)));
    int Tc = (int)((tcap / 128) * 128);
    if (Tc < 128) Tc = 128;
    if (Tc > Tn) Tc = Tn;

    detect_kernel<<<1, 256, 0, stream>>>((const unsigned int*)x, flag);
    cvt_x_kernel<<<(Tn * Dd) / 256, 256, 0, stream>>>(x, flag, xb);
    gate_kernel<<<Tn, 64, 0, stream>>>(x, gate_w, gate_b, flag, coef);
    init_acc_kernel<<<(Tn * Oo) / 256, 256, 0, stream>>>(coef, sb2, rb2, flag, accb);

    dim3 tb(32, 8);
    for (int j = 0; j < NEXP; ++j) {
        const void* w1 = (j < 2) ? sw1 : rw1;
        const void* w2 = (j < 2) ? sw2 : rw2;
        const void* b1 = (j < 2) ? sb1 : rb1;
        int je = (j < 2) ? j : (j - 2);
        size_t w1_e = (size_t)je * Dd * Ff;
        size_t w2_e = (size_t)je * Ff * Oo;
        size_t b1_e = (size_t)je * Ff;

        cvt_transpose_kernel<<<dim3(Ff / 32, Dd / 32), tb, 0, stream>>>(w1, w1_e, flag, W1T, Dd, Ff);
        cvt_transpose_kernel<<<dim3(Oo / 32, Ff / 32), tb, 0, stream>>>(w2, w2_e, flag, W2T, Ff, Oo);

        for (int tok0 = 0; tok0 < Tn; tok0 += Tc) {
            int tc = (Tn - tok0 < Tc) ? (Tn - tok0) : Tc;
            gemm_kernel<1><<<dim3(tc / 128, Ff / 128), 256, 0, stream>>>(
                xb + (size_t)tok0 * Dd, W1T, tc, Ff, Dd,
                b1, b1_e, flag, coef + (size_t)tok0 * 8 + j, Hs, nullptr);
            gemm_kernel<2><<<dim3(tc / 128, Oo / 128), 256, 0, stream>>>(
                Hs, W2T, tc, Oo, Ff, nullptr, 0, flag, nullptr, nullptr, accb + (size_t)tok0 * Oo);
        }
    }

    convert_kernel<<<(Tn * Oo) / 256, 256, 0, stream>>>(accb, flag, d_out);
}

// Round 5
// 1237.179 us; speedup vs baseline: 1.9558x; 1.9558x over previous
//
#include <hip/hip_runtime.h>

typedef __bf16 bf16_t;
typedef __bf16 bf16x8 __attribute__((ext_vector_type(8)));
typedef float f32x4 __attribute__((ext_vector_type(4)));

// Problem constants
constexpr int Tn = 4 * 2048;   // tokens = B*S
constexpr int Dd = 1024;
constexpr int Ff = 4096;
constexpr int Oo = 1024;
constexpr int NEXP = 6;        // 2 shared + 4 routed

// flag-conditional scalar input load (inputs may be f32 or bf16; detected at runtime)
__device__ __forceinline__ float ldin(const void* p, size_t i, int isf32) {
    return isf32 ? ((const float*)p)[i] : (float)((const bf16_t*)p)[i];
}

// ---------------- dtype detector ----------------
__global__ void detect_kernel(const unsigned int* __restrict__ xw, int* __restrict__ flag) {
    __shared__ int cnt;
    if (threadIdx.x == 0) cnt = 0;
    __syncthreads();
    int c = 0;
    for (int i = threadIdx.x; i < 16384; i += 256) {
        unsigned w = xw[i];
        if (((w >> 7) & 0xFFu) == 0xFFu) ++c;
    }
    atomicAdd(&cnt, c);
    __syncthreads();
    if (threadIdx.x == 0) flag[0] = (cnt >= 4) ? 1 : 0;
}

// ---------------- x -> bf16 ----------------
__global__ void cvt_x_kernel(const void* __restrict__ x, const int* __restrict__ flag,
                             bf16_t* __restrict__ xb) {
    int f = flag[0];
    size_t i = (size_t)blockIdx.x * 256 + threadIdx.x;
    xb[i] = (bf16_t)ldin(x, i, f);
}

// ---------------- convert+transpose: src(+eofs) [R][C] -> bf16 dst [C][R] ----------------
__global__ void cvt_transpose_kernel(const void* __restrict__ src, size_t eofs,
                                     const int* __restrict__ flag,
                                     bf16_t* __restrict__ dst, int R, int C) {
    __shared__ bf16_t tile[32][33];
    int f = flag[0];
    int c0 = blockIdx.x * 32, r0 = blockIdx.y * 32;
    int tx = threadIdx.x, ty = threadIdx.y;
    #pragma unroll
    for (int i = 0; i < 32; i += 8)
        tile[ty + i][tx] = (bf16_t)ldin(src, eofs + (size_t)(r0 + ty + i) * C + c0 + tx, f);
    __syncthreads();
    #pragma unroll
    for (int i = 0; i < 32; i += 8)
        dst[(size_t)(c0 + ty + i) * R + r0 + tx] = tile[tx][ty + i];
}

// ---------------- gating ----------------
__global__ void gate_kernel(const void* __restrict__ x, const void* __restrict__ gw,
                            const void* __restrict__ gb, const int* __restrict__ flag,
                            float* __restrict__ coef) {
    int f = flag[0];
    int t = blockIdx.x;
    int lane = threadIdx.x;  // 64 threads
    float a0 = 0.f, a1 = 0.f, a2 = 0.f, a3 = 0.f;
    for (int d = lane; d < Dd; d += 64) {
        float xv = ldin(x, (size_t)t * Dd + d, f);
        a0 += xv * ldin(gw, (size_t)d * 4 + 0, f);
        a1 += xv * ldin(gw, (size_t)d * 4 + 1, f);
        a2 += xv * ldin(gw, (size_t)d * 4 + 2, f);
        a3 += xv * ldin(gw, (size_t)d * 4 + 3, f);
    }
    #pragma unroll
    for (int off = 32; off; off >>= 1) {
        a0 += __shfl_xor(a0, off);
        a1 += __shfl_xor(a1, off);
        a2 += __shfl_xor(a2, off);
        a3 += __shfl_xor(a3, off);
    }
    if (lane == 0) {
        float l[4] = {a0 + ldin(gb, 0, f), a1 + ldin(gb, 1, f),
                      a2 + ldin(gb, 2, f), a3 + ldin(gb, 3, f)};
        float mx = fmaxf(fmaxf(l[0], l[1]), fmaxf(l[2], l[3]));
        float e[4], s = 0.f;
        #pragma unroll
        for (int i = 0; i < 4; ++i) { e[i] = expf(l[i] - mx); s += e[i]; }
        float w[4];
        #pragma unroll
        for (int i = 0; i < 4; ++i) w[i] = e[i] / s;
        int i0 = 0;
        for (int i = 1; i < 4; ++i) if (w[i] > w[i0]) i0 = i;   // ties -> lowest idx
        int i1 = -1;
        for (int i = 0; i < 4; ++i) { if (i == i0) continue; if (i1 < 0 || w[i] > w[i1]) i1 = i; }
        float c[8] = {0.5f, 0.5f, 0.f, 0.f, 0.f, 0.f, 0.f, 0.f};
        c[2 + i0] = w[i0];
        c[2 + i1] = w[i1];
        float* dst = coef + (size_t)t * 8;
        #pragma unroll
        for (int k = 0; k < 8; ++k) dst[k] = c[k];
    }
}

// ---------------- acc init: acc[t][o] = sum_j coef[t][j]*b2[j][o] ----------------
__global__ void init_acc_kernel(const float* __restrict__ coef, const void* __restrict__ sb2,
                                const void* __restrict__ rb2, const int* __restrict__ flag,
                                float* __restrict__ acc) {
    int f = flag[0];
    size_t idx = (size_t)blockIdx.x * 256 + threadIdx.x;
    int t = (int)(idx >> 10);          // O = 1024
    int o = (int)(idx & 1023);
    const float* c = coef + (size_t)t * 8;
    float v = c[0] * ldin(sb2, o, f) + c[1] * ldin(sb2, Oo + o, f)
            + c[2] * ldin(rb2, o, f) + c[3] * ldin(rb2, Oo + o, f)
            + c[4] * ldin(rb2, 2 * Oo + o, f) + c[5] * ldin(rb2, 3 * Oo + o, f);
    acc[idx] = v;
}

// ---------------- final convert ----------------
__global__ void convert_kernel(const float* __restrict__ acc, const int* __restrict__ flag,
                               void* __restrict__ out) {
    int f = flag[0];
    size_t idx = (size_t)blockIdx.x * 256 + threadIdx.x;
    float v = acc[idx];
    if (v != v) v = 333.0f;   // NaN sentinel for diagnosis
    if (f) ((float*)out)[idx] = v;
    else   ((bf16_t*)out)[idx] = (bf16_t)v;
}

// ---------------- GEMM core: C = A[M,K] * Bt[N,K]^T, 128x128 tile, BK=64 ----------------
// global_load_lds width-16 staging + XOR bank-swizzle:
//   LDS slot (row, c8s) holds global chunk k8 = c8s ^ (row&7)   (chunks of 8 bf16 = 16 B)
//   glds dst stays wave-uniform-base + lane*16 (required); only global src is permuted.
// MODE 1: obf = bf16( relu(acc + bias[b1_e+n]) * coef[m*8] );  MODE 2: oacc += acc
template <int MODE>
__launch_bounds__(256, 2)
__global__ void gemm_kernel(const bf16_t* __restrict__ A, const bf16_t* __restrict__ Bt,
                            int M, int N, int K,
                            const void* __restrict__ bias, size_t b1_e,
                            const int* __restrict__ flag,
                            const float* __restrict__ coef,
                            bf16_t* __restrict__ obf, float* __restrict__ oacc) {
    constexpr int BM = 128, BN = 128, BK = 64;
    __shared__ __align__(16) bf16_t Al[BM * BK];
    __shared__ __align__(16) bf16_t Bl[BN * BK];

    const int tid = threadIdx.x;
    const int lane = tid & 63;
    const int wave = tid >> 6;
    const int wm = wave & 1, wn = wave >> 1;   // 2x2 wave grid, each wave 64x64
    const int bm = blockIdx.x * BM;
    const int bn = blockIdx.y * BN;
    const int l15 = lane & 15;
    const int l4 = lane >> 4;
    const int r7 = l15 & 7;                    // row&7 for fragment rows (rows are l15 mod 16)

    f32x4 acc[4][4] = {};

    for (int k0 = 0; k0 < K; k0 += BK) {
        #pragma unroll
        for (int it = 0; it < 4; ++it) {
            int q = it * 256 + tid;
            int row = q >> 3, c8s = q & 7;
            int k8 = c8s ^ (row & 7);
            const bf16_t* g = A + (size_t)(bm + row) * K + k0 + k8 * 8;
            __builtin_amdgcn_global_load_lds(
                (const __attribute__((address_space(1))) unsigned int*)g,
                (__attribute__((address_space(3))) unsigned int*)(&Al[q * 8]), 16, 0, 0);
        }
        #pragma unroll
        for (int it = 0; it < 4; ++it) {
            int q = it * 256 + tid;
            int row = q >> 3, c8s = q & 7;
            int k8 = c8s ^ (row & 7);
            const bf16_t* g = Bt + (size_t)(bn + row) * K + k0 + k8 * 8;
            __builtin_amdgcn_global_load_lds(
                (const __attribute__((address_space(1))) unsigned int*)g,
                (__attribute__((address_space(3))) unsigned int*)(&Bl[q * 8]), 16, 0, 0);
        }
        __syncthreads();   // emits s_waitcnt vmcnt(0) before s_barrier -> LDS valid
        #pragma unroll
        for (int kk = 0; kk < BK; kk += 32) {
            const int k8f = l4 + (kk >> 3);    // which 8-elem chunk this lane's fragment wants
            const int c8s = (k8f ^ r7) * 8;    // swizzled LDS chunk offset (elements)
            bf16x8 af[4], bfv[4];
            #pragma unroll
            for (int i = 0; i < 4; ++i)
                af[i] = *(const bf16x8*)&Al[(wm * 64 + i * 16 + l15) * BK + c8s];
            #pragma unroll
            for (int j = 0; j < 4; ++j)
                bfv[j] = *(const bf16x8*)&Bl[(wn * 64 + j * 16 + l15) * BK + c8s];
            #pragma unroll
            for (int i = 0; i < 4; ++i)
                #pragma unroll
                for (int j = 0; j < 4; ++j)
                    acc[i][j] = __builtin_amdgcn_mfma_f32_16x16x32_bf16(af[i], bfv[j], acc[i][j], 0, 0, 0);
        }
        __syncthreads();
    }

    if (MODE == 1) {
        int isf32 = flag[0];
        float bz[4];
        #pragma unroll
        for (int j = 0; j < 4; ++j)
            bz[j] = ldin(bias, b1_e + (size_t)(bn + wn * 64 + j * 16 + l15), isf32);
        #pragma unroll
        for (int i = 0; i < 4; ++i) {
            #pragma unroll
            for (int r = 0; r < 4; ++r) {
                int m = bm + wm * 64 + i * 16 + l4 * 4 + r;
                float cf = coef[(size_t)m * 8];
                #pragma unroll
                for (int j = 0; j < 4; ++j) {
                    float v = acc[i][j][r] + bz[j];
                    v = fmaxf(v, 0.f) * cf;
                    obf[(size_t)m * N + bn + wn * 64 + j * 16 + l15] = (bf16_t)v;
                }
            }
        }
    } else {
        #pragma unroll
        for (int i = 0; i < 4; ++i) {
            #pragma unroll
            for (int r = 0; r < 4; ++r) {
                int m = bm + wm * 64 + i * 16 + l4 * 4 + r;
                float* orow = oacc + (size_t)m * N + bn + wn * 64 + l15;
                #pragma unroll
                for (int j = 0; j < 4; ++j)
                    orow[j * 16] += acc[i][j][r];
            }
        }
    }
}

// ---------------- launcher ----------------
extern "C" void kernel_launch(void* const* d_in, const int* in_sizes, int n_in,
                              void* d_out, int out_size, void* d_ws, size_t ws_size,
                              hipStream_t stream) {
    const void* x      = d_in[0];
    const void* gate_w = d_in[1];
    const void* gate_b = d_in[2];
    const void* sw1    = d_in[3];
    const void* sb1    = d_in[4];
    const void* sw2    = d_in[5];
    const void* sb2    = d_in[6];
    const void* rw1    = d_in[7];
    const void* rb1    = d_in[8];
    const void* rw2    = d_in[9];
    const void* rb2    = d_in[10];

    char* ws = (char*)d_ws;
    int* flag = (int*)ws;
    size_t off = 256;
    bf16_t* W1T = (bf16_t*)(ws + off); off += (size_t)Ff * Dd * sizeof(bf16_t);  // 8 MB
    bf16_t* W2T = (bf16_t*)(ws + off); off += (size_t)Oo * Ff * sizeof(bf16_t);  // 8 MB
    bf16_t* xb  = (bf16_t*)(ws + off); off += (size_t)Tn * Dd * sizeof(bf16_t);  // 16 MB
    float* coef = (float*)(ws + off);  off += (size_t)Tn * 8 * sizeof(float);    // 256 KB
    float* accb = (float*)(ws + off);  off += (size_t)Tn * Oo * sizeof(float);   // 32 MB
    bf16_t* Hs  = (bf16_t*)(ws + off);
    size_t rem = (ws_size > off) ? (ws_size - off) : 0;
    long tcap = (long)(rem / ((size_t)Ff * sizeof(bf16_t)));
    int Tc = (int)((tcap / 128) * 128);
    if (Tc < 128) Tc = 128;
    if (Tc > Tn) Tc = Tn;

    detect_kernel<<<1, 256, 0, stream>>>((const unsigned int*)x, flag);
    cvt_x_kernel<<<(Tn * Dd) / 256, 256, 0, stream>>>(x, flag, xb);
    gate_kernel<<<Tn, 64, 0, stream>>>(x, gate_w, gate_b, flag, coef);
    init_acc_kernel<<<(Tn * Oo) / 256, 256, 0, stream>>>(coef, sb2, rb2, flag, accb);

    dim3 tb(32, 8);
    for (int j = 0; j < NEXP; ++j) {
        const void* w1 = (j < 2) ? sw1 : rw1;
        const void* w2 = (j < 2) ? sw2 : rw2;
        const void* b1 = (j < 2) ? sb1 : rb1;
        int je = (j < 2) ? j : (j - 2);
        size_t w1_e = (size_t)je * Dd * Ff;
        size_t w2_e = (size_t)je * Ff * Oo;
        size_t b1_e = (size_t)je * Ff;

        cvt_transpose_kernel<<<dim3(Ff / 32, Dd / 32), tb, 0, stream>>>(w1, w1_e, flag, W1T, Dd, Ff);
        cvt_transpose_kernel<<<dim3(Oo / 32, Ff / 32), tb, 0, stream>>>(w2, w2_e, flag, W2T, Ff, Oo);

        for (int tok0 = 0; tok0 < Tn; tok0 += Tc) {
            int tc = (Tn - tok0 < Tc) ? (Tn - tok0) : Tc;
            gemm_kernel<1><<<dim3(tc / 128, Ff / 128), 256, 0, stream>>>(
                xb + (size_t)tok0 * Dd, W1T, tc, Ff, Dd,
                b1, b1_e, flag, coef + (size_t)tok0 * 8 + j, Hs, nullptr);
            gemm_kernel<2><<<dim3(tc / 128, Oo / 128), 256, 0, stream>>>(
                Hs, W2T, tc, Oo, Ff, nullptr, 0, flag, nullptr, nullptr, accb + (size_t)tok0 * Oo);
        }
    }

    convert_kernel<<<(Tn * Oo) / 256, 256, 0, stream>>>(accb, flag, d_out);
}